// Round 5
// baseline (311.435 us; speedup 1.0000x reference)
//
#include <hip/hip_runtime.h>

#define D 128
#define N_CLS 40

// ---------------------------------------------------------------------------
// bf16 helpers (RNE)
// ---------------------------------------------------------------------------
__device__ __forceinline__ unsigned f2bf(float f) {
  unsigned u = __builtin_bit_cast(unsigned, f);
  u += 0x7fffu + ((u >> 16) & 1u);
  return u >> 16;
}
__device__ __forceinline__ float bf_lo(unsigned u) {
  return __builtin_bit_cast(float, u << 16);
}
__device__ __forceinline__ float bf_hi(unsigned u) {
  return __builtin_bit_cast(float, u & 0xffff0000u);
}

// ---------------------------------------------------------------------------
// CSR build step 1: counts[dst[e]]++
// ---------------------------------------------------------------------------
__global__ __launch_bounds__(256) void count_kernel(
    const int* __restrict__ dst, int* __restrict__ counts, int n_edges) {
  int e = blockIdx.x * 256 + threadIdx.x;
  if (e < n_edges) atomicAdd(&counts[dst[e]], 1);
}

// 3-phase device-wide exclusive scan over counts[n] (n % 4 == 0).
__global__ __launch_bounds__(256) void scan_partA(
    const int* __restrict__ counts, int* __restrict__ partials, int n4) {
  __shared__ int sh[256];
  const int tid = threadIdx.x;
  const int g = blockIdx.x * 256 + tid;
  int s = 0;
  if (g < n4) {
    const int4 c = reinterpret_cast<const int4*>(counts)[g];
    s = c.x + c.y + c.z + c.w;
  }
  sh[tid] = s;
  __syncthreads();
  for (int off = 128; off > 0; off >>= 1) {
    if (tid < off) sh[tid] += sh[tid + off];
    __syncthreads();
  }
  if (tid == 0) partials[blockIdx.x] = sh[0];
}

__global__ __launch_bounds__(64) void scan_partB(
    int* __restrict__ partials, int* __restrict__ row_start, int nP,
    int n, int n_edges) {
  const int lane = threadIdx.x;
  int v = (lane < nP) ? partials[lane] : 0;
  int x = v;
  for (int off = 1; off < 64; off <<= 1) {
    int y = __shfl_up(x, off, 64);
    if (lane >= off) x += y;
  }
  if (lane < nP) partials[lane] = x - v;
  if (lane == 0) row_start[n] = n_edges;
}

__global__ __launch_bounds__(256) void scan_partC(
    int* __restrict__ counts, const int* __restrict__ partials,
    int* __restrict__ row_start, int n4) {
  __shared__ int sh[256];
  const int tid = threadIdx.x;
  const int g = blockIdx.x * 256 + tid;
  int4 c = make_int4(0, 0, 0, 0);
  if (g < n4) c = reinterpret_cast<const int4*>(counts)[g];
  const int s0 = c.x;
  const int s1 = s0 + c.y;
  const int s2 = s1 + c.z;
  const int s3 = s2 + c.w;
  sh[tid] = s3;
  __syncthreads();
  for (int off = 1; off < 256; off <<= 1) {
    int y = (tid >= off) ? sh[tid - off] : 0;
    __syncthreads();
    sh[tid] += y;
    __syncthreads();
  }
  if (g < n4) {
    const int base = partials[blockIdx.x] + sh[tid] - s3;
    const int4 rs = make_int4(base, base + s0, base + s1, base + s2);
    reinterpret_cast<int4*>(row_start)[g] = rs;
    reinterpret_cast<int4*>(counts)[g] = rs;
  }
}

__global__ __launch_bounds__(256) void fill_kernel(
    const int* __restrict__ src, const int* __restrict__ dst,
    int* __restrict__ cursor, int* __restrict__ col_idx, int n_edges) {
  int e = blockIdx.x * 256 + threadIdx.x;
  if (e < n_edges) {
    int p = atomicAdd(&cursor[dst[e]], 1);
    col_idx[p] = src[e];
  }
}

// ---------------------------------------------------------------------------
// Merged converter: blocks [0, nxb) convert x (float4 -> 2x packed bf16),
// blocks [nxb, nxb+17) convert W0/W1/W2 (W2 padded to 48 rows).
// ---------------------------------------------------------------------------
__global__ __launch_bounds__(256) void convert_all(
    const float4* __restrict__ x4, uint2* __restrict__ xb, int n4, int nxb,
    const float* __restrict__ W0, const float* __restrict__ W1,
    const float* __restrict__ W2, unsigned short* __restrict__ W0b,
    unsigned short* __restrict__ W1b, unsigned short* __restrict__ W2b) {
  if ((int)blockIdx.x < nxb) {
    int i = blockIdx.x * 256 + threadIdx.x;
    if (i < n4) {
      float4 v = x4[i];
      xb[i] = make_uint2(f2bf(v.x) | (f2bf(v.y) << 16),
                         f2bf(v.z) | (f2bf(v.w) << 16));
    }
  } else {
    int idx = (blockIdx.x - nxb) * 256 + threadIdx.x;
    const int n0 = 128 * 128, n1 = 128 * 128, n2 = 48 * 128;
    if (idx < n0) {
      W0b[idx] = (unsigned short)f2bf(W0[idx]);
    } else if (idx < n0 + n1) {
      int i = idx - n0;
      W1b[i] = (unsigned short)f2bf(W1[i]);
    } else if (idx < n0 + n1 + n2) {
      int i = idx - n0 - n1;
      int r = i >> 7;
      W2b[i] = (r < N_CLS) ? (unsigned short)f2bf(W2[i]) : (unsigned short)0;
    }
  }
}

// ---------------------------------------------------------------------------
// Fused layer: out = act( (H + segsum(H[src],dst)) @ B^T + bias )
// Block = 256 thr = 4 waves; 64 nodes/block; wave w owns rows blk*64+w*16..+15.
// Lane (r16=lane&15, quad=lane>>4) gathers row node=m_base+r16, k-chunks
// quad*8+ks*32 .. +7 directly into fp32 A-fragment accumulators (no LDS).
// Then 4x mfma_f32_16x16x32_bf16 per n-tile. C/D: col=lane&15, row=quad*4+reg.
// ---------------------------------------------------------------------------
typedef __attribute__((ext_vector_type(8))) short bf16x8;
typedef __attribute__((ext_vector_type(4))) float f32x4;

__device__ __forceinline__ void unpack_acc(uint4 v, float* a) {
  a[0] += bf_lo(v.x); a[1] += bf_hi(v.x);
  a[2] += bf_lo(v.y); a[3] += bf_hi(v.y);
  a[4] += bf_lo(v.z); a[5] += bf_hi(v.z);
  a[6] += bf_lo(v.w); a[7] += bf_hi(v.w);
}

template <int NT, bool RELU, bool OUTBF16>
__global__ __launch_bounds__(256) void fused_layer(
    const unsigned short* __restrict__ H, const int* __restrict__ row_start,
    const int* __restrict__ col_idx, const unsigned short* __restrict__ B,
    const float* __restrict__ bias, void* __restrict__ out,
    int M, int ncols) {
  const int lane = threadIdx.x & 63;
  const int wv = threadIdx.x >> 6;
  const int r16 = lane & 15;
  const int quad = lane >> 4;
  const int m_base = blockIdx.x * 64 + wv * 16;
  const int node = m_base + r16;
  const bool valid = node < M;

  // ---- gather phase: fp32 accumulators, a[ks*8+j] holds k = ks*32+quad*8+j
  float a[32];
  const uint4* Hv = reinterpret_cast<const uint4*>(H);  // 16 uint4 per row
#pragma unroll
  for (int i = 0; i < 32; ++i) a[i] = 0.f;

  if (valid) {
    const uint4* sp = Hv + (size_t)node * 16 + quad;
#pragma unroll
    for (int ks = 0; ks < 4; ++ks) unpack_acc(sp[ks * 4], a + ks * 8);
  }

  int s = valid ? row_start[node] : 0;
  int e = valid ? row_start[node + 1] : 0;
  int j = s;
  for (; j + 1 < e; j += 2) {
    int u0 = col_idx[j];
    int u1 = col_idx[j + 1];
    const uint4* p0 = Hv + (size_t)u0 * 16 + quad;
    const uint4* p1 = Hv + (size_t)u1 * 16 + quad;
    uint4 v00 = p0[0], v01 = p0[4], v02 = p0[8], v03 = p0[12];
    uint4 v10 = p1[0], v11 = p1[4], v12 = p1[8], v13 = p1[12];
    unpack_acc(v00, a + 0);  unpack_acc(v01, a + 8);
    unpack_acc(v02, a + 16); unpack_acc(v03, a + 24);
    unpack_acc(v10, a + 0);  unpack_acc(v11, a + 8);
    unpack_acc(v12, a + 16); unpack_acc(v13, a + 24);
  }
  if (j < e) {
    int u = col_idx[j];
    const uint4* p = Hv + (size_t)u * 16 + quad;
    unpack_acc(p[0], a + 0);  unpack_acc(p[4], a + 8);
    unpack_acc(p[8], a + 16); unpack_acc(p[12], a + 24);
  }

  // ---- pack A fragments (bf16)
  union Frag { bf16x8 v; unsigned u[4]; };
  Frag af[4];
#pragma unroll
  for (int ks = 0; ks < 4; ++ks)
#pragma unroll
    for (int d = 0; d < 4; ++d)
      af[ks].u[d] = f2bf(a[ks * 8 + 2 * d]) | (f2bf(a[ks * 8 + 2 * d + 1]) << 16);

  // ---- MFMA phase
  f32x4 acc[NT];
#pragma unroll
  for (int nt = 0; nt < NT; ++nt) {
    acc[nt] = (f32x4){0.f, 0.f, 0.f, 0.f};
    const short* Bp = (const short*)B + (size_t)(nt * 16 + r16) * D + quad * 8;
#pragma unroll
    for (int ks = 0; ks < 4; ++ks) {
      bf16x8 bf = *reinterpret_cast<const bf16x8*>(Bp + ks * 32);
      acc[nt] = __builtin_amdgcn_mfma_f32_16x16x32_bf16(af[ks].v, bf, acc[nt], 0, 0, 0);
    }
  }

  // ---- epilogue
  const int orow = m_base + quad * 4;
#pragma unroll
  for (int nt = 0; nt < NT; ++nt) {
    int col = nt * 16 + r16;
    float bv = (col < ncols) ? bias[col] : 0.f;
#pragma unroll
    for (int r = 0; r < 4; ++r) {
      int grow = orow + r;
      if (grow < M && col < ncols) {
        float v = acc[nt][r] + bv;
        if (RELU) v = fmaxf(v, 0.f);
        if (OUTBF16)
          ((unsigned short*)out)[(size_t)grow * D + col] = (unsigned short)f2bf(v);
        else
          ((float*)out)[(size_t)grow * ncols + col] = v;
      }
    }
  }
}

// ---------------------------------------------------------------------------
extern "C" void kernel_launch(void* const* d_in, const int* in_sizes, int n_in,
                              void* d_out, int out_size, void* d_ws, size_t ws_size,
                              hipStream_t stream) {
  const float* x   = (const float*)d_in[0];
  const int*   src = (const int*)d_in[1];
  const int*   dst = (const int*)d_in[2];
  const float* W0  = (const float*)d_in[3];
  const float* b0  = (const float*)d_in[4];
  const float* W1  = (const float*)d_in[5];
  const float* b1  = (const float*)d_in[6];
  const float* W2  = (const float*)d_in[7];
  const float* b2  = (const float*)d_in[8];
  float* out = (float*)d_out;

  const int M = in_sizes[0] / D;  // 50000
  const int E = in_sizes[1];      // 600000

  // ws layout (16B-aligned chunks):
  // [xb bf16 M*128][h0 bf16 M*128][h1 bf16 M*128][W0b][W1b][W2b 48x128]
  // [counts M][row_start M+4][col_idx E][partials 64]
  char* p = (char*)d_ws;
  unsigned short* xb = (unsigned short*)p;  p += (size_t)M * D * 2;
  unsigned short* h0 = (unsigned short*)p;  p += (size_t)M * D * 2;
  unsigned short* h1 = (unsigned short*)p;  p += (size_t)M * D * 2;
  unsigned short* W0b = (unsigned short*)p;  p += 128 * 128 * 2;
  unsigned short* W1b = (unsigned short*)p;  p += 128 * 128 * 2;
  unsigned short* W2b = (unsigned short*)p;  p += 48 * 128 * 2;
  int* counts    = (int*)p;  p += (size_t)M * 4;
  int* row_start = (int*)p;  p += (size_t)(M + 4) * 4;
  int* col_idx   = (int*)p;  p += (size_t)E * 4;
  int* partials  = (int*)p;

  const int n4 = M / 4;
  const int scanBlocks = (n4 + 255) / 256;
  const int edgeBlocks = (E + 255) / 256;
  const int fusedBlocks = (M + 63) / 64;

  const int xConv4 = M * D / 4;                       // float4 groups in x
  const int nxb = (xConv4 + 255) / 256;               // conv-x blocks
  const int nwb = (128 * 128 * 2 + 48 * 128 + 255) / 256;  // conv-w blocks

  // --- CSR build ---
  hipMemsetAsync(counts, 0, (size_t)M * sizeof(int), stream);
  count_kernel<<<edgeBlocks, 256, 0, stream>>>(dst, counts, E);
  scan_partA<<<scanBlocks, 256, 0, stream>>>(counts, partials, n4);
  scan_partB<<<1, 64, 0, stream>>>(partials, row_start, scanBlocks, M, E);
  scan_partC<<<scanBlocks, 256, 0, stream>>>(counts, partials, row_start, n4);
  fill_kernel<<<edgeBlocks, 256, 0, stream>>>(src, dst, counts, col_idx, E);

  // --- Convert x + weights to bf16 (one kernel) ---
  convert_all<<<nxb + nwb, 256, 0, stream>>>(
      (const float4*)x, (uint2*)xb, xConv4, nxb, W0, W1, W2, W0b, W1b, W2b);

  // --- Fused layers ---
  fused_layer<8, true, true><<<fusedBlocks, 256, 0, stream>>>(
      xb, row_start, col_idx, W0b, b0, h0, M, D);
  fused_layer<8, true, true><<<fusedBlocks, 256, 0, stream>>>(
      h0, row_start, col_idx, W1b, b1, h1, M, D);
  fused_layer<3, false, false><<<fusedBlocks, 256, 0, stream>>>(
      h1, row_start, col_idx, W2b, b2, out, M, N_CLS);
}